// Round 8
// baseline (103.513 us; speedup 1.0000x reference)
//
#include <hip/hip_runtime.h>

// LIF scan over t=0..63, 1M neurons, fp32. 256 MB in + 256 MB out.
// Ladder: R1 124us; R2 119us; R3 float2 NT-both 102.3us; R4 117us;
// R5 float2 cached-load+NT-store 79.6us; R6 BATCH=8 94.4us (regr);
// R7 explicit input partition 78.8us (neutral -- hit fraction unchanged).
//
// Post-mortem R3/R5/R7: effective HBM rate is constant ~5.1-5.25 TB/s in
// every config; all gains were TRAFFIC reduction. Remaining bytes: 268 MB
// of output writes every replay -- to the SAME addresses. R8 inverts the
// cache policy: let the OUTPUT own the Infinity Cache.
//   - NT loads: input never allocates in MALL (R3-vs-R5 proved nt-loads
//     don't allocate), reads stream 268 MB from HBM each replay.
//   - REGULAR stores: L2-allocate -> writeback -> MALL absorbs; replays
//     rewrite the same 268 MB so dirty lines are re-hit in MALL and HBM
//     write traffic collapses (268 MB output vs 256 MB MALL ~= 90%+
//     absorption). Discriminator: if MALL write-arounds instead, we get
//     ~102us (R3-like) and R5's 79us is the declared roofline.
//
// Rounding discipline unchanged (absmax==0 all rounds): du = 0.5*(ir-u),
// u_t = du + u as separate __f*_rn ops; fma contraction would flip
// threshold crossings and fork entire neuron trajectories.

typedef float f32x2 __attribute__((ext_vector_type(2)));

constexpr int T_STEPS = 64;
constexpr int NS      = 32 * 32768;     // neurons per timestep
constexpr int NS2     = NS / 2;         // float2 chunks per timestep (524288)
constexpr int BATCH   = 4;
constexpr int NBATCH  = T_STEPS / BATCH;   // 16

__global__ __launch_bounds__(256, 8)
void LIF_61263413510486_kernel(const float* __restrict__ ir,
                               float* __restrict__ o) {
    const int i = blockIdx.x * blockDim.x + threadIdx.x;  // float2 index in plane
    const f32x2* __restrict__ src = reinterpret_cast<const f32x2*>(ir) + i;
    f32x2* __restrict__ dst = reinterpret_cast<f32x2*>(o) + i;

    f32x2 buf[2][BATCH];
    float u[2] = {0.0f, 0.0f};

    #pragma unroll
    for (int k = 0; k < BATCH; ++k)
        buf[0][k] = __builtin_nontemporal_load(src + (size_t)k * NS2);

    #pragma unroll
    for (int tb = 0; tb < NBATCH; ++tb) {
        const int cur = tb & 1;        // compile-time after full unroll
        const int nxt = cur ^ 1;
        if (tb + 1 < NBATCH) {
            #pragma unroll
            for (int k = 0; k < BATCH; ++k)
                buf[nxt][k] = __builtin_nontemporal_load(
                    src + (size_t)((tb + 1) * BATCH + k) * NS2);
        }
        #pragma unroll
        for (int k = 0; k < BATCH; ++k) {
            const f32x2 x = buf[cur][k];
            f32x2 ov;
            #pragma unroll
            for (int j = 0; j < 2; ++j) {
                const float du = __fmul_rn(0.5f, __fsub_rn(x[j], u[j]));
                const float ut = __fadd_rn(du, u[j]);
                const bool spike = (ut >= 1.0f);   // heaviside(u_t - 1.0)
                ov[j] = spike ? 1.0f : 0.0f;
                u[j]  = spike ? 0.0f : ut;          // u*(1-o) + 0*o exactly
            }
            // REGULAR store: allocate -> MALL writeback absorption across replays
            dst[(size_t)(tb * BATCH + k) * NS2] = ov;
        }
    }
}

extern "C" void kernel_launch(void* const* d_in, const int* in_sizes, int n_in,
                              void* d_out, int out_size, void* d_ws, size_t ws_size,
                              hipStream_t stream) {
    const float* ir = (const float*)d_in[0];
    float* o = (float*)d_out;

    const int threads = 256;
    const int blocks  = NS2 / threads;   // 2048
    LIF_61263413510486_kernel<<<blocks, threads, 0, stream>>>(ir, o);
}